// Round 8
// baseline (415.276 us; speedup 1.0000x reference)
//
#include <hip/hip_runtime.h>
#include <stdint.h>

// BiMultiHeadAttention (GLIP bi-attention), MI355X bf16 MFMA pipeline.
// B=32 VN=576 LN=128 E=1024 H=16 D=64, V_DIM=1024 L_DIM=768, SCALE=0.25.

typedef unsigned short bfu;   // bf16 storage
typedef __attribute__((ext_vector_type(4))) float f32x4;
typedef __attribute__((ext_vector_type(8))) short short8;
typedef __attribute__((ext_vector_type(4))) unsigned short u16x4;

#define MFMA16(a,b,c) __builtin_amdgcn_mfma_f32_16x16x32_bf16((a),(b),(c),0,0,0)
#define SCALE_QK 0.25f

__device__ __forceinline__ unsigned short f2bf(float x) {
  unsigned int u = __float_as_uint(x);
  u += 0x7fffu + ((u >> 16) & 1u);   // round-to-nearest-even
  return (unsigned short)(u >> 16);
}

__device__ __forceinline__ void gload_lds16(const void* g, void* l) {
  __builtin_amdgcn_global_load_lds(
      reinterpret_cast<__attribute__((address_space(1))) void*>(
          reinterpret_cast<uintptr_t>(g)),
      reinterpret_cast<__attribute__((address_space(3))) void*>(
          (uint32_t)reinterpret_cast<uintptr_t>(l)),
      16, 0, 0);
}

// ---------------------------------------------------------------- converts
__global__ void cvt_f32_bf16(const float* __restrict__ x, bfu* __restrict__ y, int n4) {
  for (int i = blockIdx.x * blockDim.x + threadIdx.x; i < n4; i += gridDim.x * blockDim.x) {
    const float4 f = *reinterpret_cast<const float4*>(x + (size_t)i * 4);
    u16x4 o;
    o[0] = f2bf(f.x); o[1] = f2bf(f.y); o[2] = f2bf(f.z); o[3] = f2bf(f.w);
    *reinterpret_cast<u16x4*>(y + (size_t)i * 4) = o;
  }
}

struct CvtArgs {
  const float* src[7];
  bfu* dst[7];
  int n4[7];
};

__global__ void cvt_multi(CvtArgs a) {
  const int s = blockIdx.y;
  const float* __restrict__ x = a.src[s];
  bfu* __restrict__ y = a.dst[s];
  const int n4 = a.n4[s];
  for (int i = blockIdx.x * blockDim.x + threadIdx.x; i < n4; i += gridDim.x * blockDim.x) {
    const float4 f = *reinterpret_cast<const float4*>(x + (size_t)i * 4);
    u16x4 o;
    o[0] = f2bf(f.x); o[1] = f2bf(f.y); o[2] = f2bf(f.z); o[3] = f2bf(f.w);
    *reinterpret_cast<u16x4*>(y + (size_t)i * 4) = o;
  }
}

// ---------------------------------------------------------------- GEMM 128-tile (m97 structure) — R5 version
__global__ __launch_bounds__(256) void gemm_bt(
    const bfu* __restrict__ A, const bfu* __restrict__ W, const float* __restrict__ bias,
    bfu* __restrict__ Cb, float* __restrict__ Cf, bfu* __restrict__ Ct, int R, int colsplit,
    int ldc, int M, int N, int K, int nbn)
{
  __shared__ bfu As[128 * 32];
  __shared__ bfu Bs[128 * 32];
  const int nbm = M >> 7;
  const int bid = blockIdx.x;
  int bm, bn;
  if ((nbm & 7) == 0) {             // bijective XCD-aware swizzle
    const int xcd = bid & 7, j = bid >> 3;
    const int jm = j / nbn;
    bm = xcd * (nbm >> 3) + jm;
    bn = j - jm * nbn;
  } else { bm = bid / nbn; bn = bid - (bid / nbn) * nbn; }

  const int t = threadIdx.x, l = t & 63, w = t >> 6;
  const int g = l >> 4, c = l & 15;
  const int wr = (w >> 1) * 64, wc = (w & 1) * 64;

  f32x4 zero = {0.f, 0.f, 0.f, 0.f};
  f32x4 acc[4][4];
  for (int m = 0; m < 4; ++m)
    for (int n = 0; n < 4; ++n) acc[m][n] = zero;

  const int rowA = l >> 2;
  const int kb   = (l & 3) * 16;

  for (int k0 = 0; k0 < K; k0 += 32) {
#pragma unroll
    for (int i = 0; i < 2; ++i) {
      int chunk = w * 2 + i;
      int r = chunk * 16 + rowA;
      const char* ga = (const char*)(A + (size_t)(bm * 128 + r) * K + k0) + kb;
      const char* gb = (const char*)(W + (size_t)(bn * 128 + r) * K + k0) + kb;
      gload_lds16(ga, (char*)As + chunk * 1024);
      gload_lds16(gb, (char*)Bs + chunk * 1024);
    }
    __syncthreads();
    short8 a[4], bf[4];
#pragma unroll
    for (int m = 0; m < 4; ++m)
      a[m] = *reinterpret_cast<const short8*>(&As[(wr + m * 16 + c) * 32 + g * 8]);
#pragma unroll
    for (int n = 0; n < 4; ++n)
      bf[n] = *reinterpret_cast<const short8*>(&Bs[(wc + n * 16 + c) * 32 + g * 8]);
#pragma unroll
    for (int m = 0; m < 4; ++m)
#pragma unroll
      for (int n = 0; n < 4; ++n)
        acc[m][n] = MFMA16(a[m], bf[n], acc[m][n]);
    __syncthreads();
  }

#pragma unroll
  for (int n = 0; n < 4; ++n) {
    const int col = bn * 128 + wc + n * 16 + c;
    const float bs = bias[col];
    if (col >= colsplit) {
      const int colp = col - colsplit;
      const int hh = colp >> 6, dd = colp & 63;
#pragma unroll
      for (int m = 0; m < 4; ++m) {
        const int row0 = bm * 128 + wr + m * 16 + g * 4;
        const int bb = row0 / R, q0 = row0 - bb * R;
        u16x4 pk;
#pragma unroll
        for (int r = 0; r < 4; ++r) pk[r] = f2bf(acc[m][n][r] + bs);
        *reinterpret_cast<u16x4*>(Ct + ((size_t)(bb * 16 + hh) * 64 + dd) * R + q0) = pk;
      }
    } else {
#pragma unroll
      for (int m = 0; m < 4; ++m) {
        const int row0 = bm * 128 + wr + m * 16 + g * 4;
#pragma unroll
        for (int r = 0; r < 4; ++r) {
          float val = acc[m][n][r] + bs;
          size_t idx = (size_t)(row0 + r) * ldc + col;
          if (Cf) Cf[idx] = val;
          else    Cb[idx] = f2bf(val);
        }
      }
    }
  }
}

// ---------------------------------------------------------------- GEMM 256-tile, deep-pipelined (3-slot ring)
// BM=BN=256, BK=32, 512 thr (8 waves: wr=w>>2 M-half, wc=w&3 N-quarter).
// LDS 96 KiB: 3 slots x (A 16KB + B 16KB). While computing tile t, tiles t+1 and t+2
// are in flight (staged 2 tiles ahead). One counted vmcnt(4) per tile, draining loads
// issued 3-4 phases (~1000 cyc) earlier -- never vmcnt(0) in the main loop.
// Both-sides swizzle: 16B slot ^= (row&3); pre-swizzled global source + swizzled ds_read.
template<int RT>
__global__ __launch_bounds__(512, 2) void gemm256(
    const bfu* __restrict__ A, const bfu* __restrict__ W, const float* __restrict__ bias,
    bfu* __restrict__ Cb, float* __restrict__ Cf, bfu* __restrict__ Ct, int colsplit,
    int ldc, int M, int N, int K, int nbn)
{
  __shared__ bfu lds[49152];          // 3 * (8192 A + 8192 B) elems = 96 KiB

  const int tid = threadIdx.x;
  const int w = tid >> 6, l = tid & 63;
  const int g = l >> 4, c = l & 15;
  const int wr = w >> 2, wc = w & 3;

  const int nbm = M >> 8;
  int bm, bn;
  { const int xcd = blockIdx.x & 7, j = blockIdx.x >> 3;
    const int jm = j / nbn; bm = xcd * (nbm >> 3) + jm; bn = j - jm * nbn; }

  const int nt = K >> 5;

  // staging: instr (op, j): rows j*128 + w*16 .. +15; lane l -> row +(l>>2), 16B slot (l&3).
  // source pre-swizzled: elem slot (l&3) ^ (row&3) = (l&3) ^ ((l>>2)&3).
  const int srow = l >> 2;
  const int swzE = (((l & 3) ^ (srow & 3)) * 8);
  const bfu* srcA = A + (size_t)(bm * 256 + w * 16 + srow) * K + swzE;
  const bfu* srcB = W + (size_t)(bn * 256 + w * 16 + srow) * K + swzE;

#define STAGE_A(s, j, k0) gload_lds16(srcA + (size_t)((j) * 128) * K + (k0), \
    (void*)(lds + (s) * 16384 + ((j) * 128 + w * 16) * 32))
#define STAGE_B(s, j, k0) gload_lds16(srcB + (size_t)((j) * 128) * K + (k0), \
    (void*)(lds + (s) * 16384 + 8192 + ((j) * 128 + w * 16) * 32))

  const int rsw = ((g ^ (c & 3)) * 8);   // read-side swizzle (elems within 32-elem row)

  short8 aLo[4], aHi[4], bF[4];
  f32x4 acc[8][4];
  const f32x4 zero = {0.f, 0.f, 0.f, 0.f};
#pragma unroll
  for (int mi = 0; mi < 8; ++mi)
#pragma unroll
    for (int ni = 0; ni < 4; ++ni) acc[mi][ni] = zero;

  // ---- prologue: stage tiles 0 and 1; wait tile 0 only
  STAGE_A(0, 0, 0);  STAGE_A(0, 1, 0);  STAGE_B(0, 0, 0);  STAGE_B(0, 1, 0);
  STAGE_A(1, 0, 32); STAGE_A(1, 1, 32); STAGE_B(1, 0, 32); STAGE_B(1, 1, 32);
  asm volatile("s_waitcnt vmcnt(4)" ::: "memory");
  __builtin_amdgcn_s_barrier();

  int s = 0;
  for (int t = 0; t < nt; ++t) {
    const int sN = (s >= 1) ? s - 1 : 2;       // (s+2)%3
    const int kf = (t + 2) * 32;
    const bool pf = (t + 2 < nt);
    // ---- phase 0: read aLo+bF of slot s; stage A(t+2); MFMA lower quadrant rows
#pragma unroll
    for (int mi = 0; mi < 4; ++mi)
      aLo[mi] = *reinterpret_cast<const short8*>(
          lds + s * 16384 + (wr * 128 + mi * 16 + c) * 32 + rsw);
#pragma unroll
    for (int ni = 0; ni < 4; ++ni)
      bF[ni] = *reinterpret_cast<const short8*>(
          lds + s * 16384 + 8192 + (wc * 64 + ni * 16 + c) * 32 + rsw);
    if (pf) { STAGE_A(sN, 0, kf); STAGE_A(sN, 1, kf); }
    __builtin_amdgcn_s_barrier();
    __builtin_amdgcn_s_setprio(1);
#pragma unroll
    for (int mi = 0; mi < 4; ++mi)
#pragma unroll
      for (int ni = 0; ni < 4; ++ni)
        acc[mi][ni] = MFMA16(aLo[mi], bF[ni], acc[mi][ni]);
    __builtin_amdgcn_s_setprio(0);
    __builtin_amdgcn_s_barrier();
    // ---- phase 1: read aHi of slot s; stage B(t+2); counted wait; MFMA upper rows
#pragma unroll
    for (int mi = 0; mi < 4; ++mi)
      aHi[mi] = *reinterpret_cast<const short8*>(
          lds + s * 16384 + (wr * 128 + (4 + mi) * 16 + c) * 32 + rsw);
    if (pf) {
      STAGE_B(sN, 0, kf); STAGE_B(sN, 1, kf);
      asm volatile("s_waitcnt vmcnt(4)" ::: "memory");   // drains tile t+1 (issued 3-4 phases ago)
    } else if (t + 1 < nt) {
      asm volatile("s_waitcnt vmcnt(0)" ::: "memory");   // drain last tile's loads once
    }
    __builtin_amdgcn_s_barrier();
    __builtin_amdgcn_s_setprio(1);
#pragma unroll
    for (int mi = 0; mi < 4; ++mi)
#pragma unroll
      for (int ni = 0; ni < 4; ++ni)
        acc[4 + mi][ni] = MFMA16(aHi[mi], bF[ni], acc[4 + mi][ni]);
    __builtin_amdgcn_s_setprio(0);
    __builtin_amdgcn_s_barrier();
    s = (s == 2) ? 0 : s + 1;
  }

  // ---- epilogue (identical to R7 layout)
#pragma unroll
  for (int ni = 0; ni < 4; ++ni) {
    const int col = bn * 256 + wc * 64 + ni * 16 + c;
    const float bs = bias[col];
    if (RT > 0 && col >= colsplit) {
      const int colp = col - colsplit;
      const int hh = colp >> 6, dd = colp & 63;
#pragma unroll
      for (int mi = 0; mi < 8; ++mi) {
        const int row0 = bm * 256 + wr * 128 + mi * 16 + g * 4;
        const int bb = row0 / (RT > 0 ? RT : 1), q0 = row0 - bb * (RT > 0 ? RT : 1);
        u16x4 pk;
#pragma unroll
        for (int r = 0; r < 4; ++r) pk[r] = f2bf(acc[mi][ni][r] + bs);
        *reinterpret_cast<u16x4*>(Ct + ((size_t)(bb * 16 + hh) * 64 + dd) * (RT > 0 ? RT : 1) + q0) = pk;
      }
    } else if (Cf) {
#pragma unroll
      for (int mi = 0; mi < 8; ++mi) {
        const int row0 = bm * 256 + wr * 128 + mi * 16 + g * 4;
#pragma unroll
        for (int r = 0; r < 4; ++r)
          Cf[(size_t)(row0 + r) * ldc + col] = acc[mi][ni][r] + bs;
      }
    } else {
#pragma unroll
      for (int mi = 0; mi < 8; ++mi) {
        const int row0 = bm * 256 + wr * 128 + mi * 16 + g * 4;
#pragma unroll
        for (int r = 0; r < 4; ++r)
          Cb[(size_t)(row0 + r) * ldc + col] = f2bf(acc[mi][ni][r] + bs);
      }
    }
  }
#undef STAGE_A
#undef STAGE_B
}

// ---------------------------------------------------------------- swizzled per-wave P-tile offsets
__device__ __forceinline__ int pvt_off(int q, int kbyte) { return q * 256 + (kbyte ^ ((q & 7) << 4)); }

// ---------------------------------------------------------------- attention stage A: xv + P^T + colsum partials
// ONE WAVE per block: grid qt*512 + bh (18432 blocks, 64 threads).
__global__ __launch_bounds__(64) void attn_xv(
    const bfu* __restrict__ Q, const bfu* __restrict__ Kl,
    const bfu* __restrict__ LVt, const float* __restrict__ mask,
    bfu* __restrict__ xv, bfu* __restrict__ PT, float* __restrict__ colpart)
{
  __shared__ short PvT[2048];         // 16x128 bf16 P tile, swizzled; reused as bounce buf

  const int blk = blockIdx.x;
  const int bh = blk & 511, qt = blk >> 9;
  const int b = bh >> 4, h = bh & 15;
  const int l = threadIdx.x;
  const int g = l >> 4, c = l & 15;

  const bfu* Qp   = Q   + ((size_t)b * 576 * 1024 + h * 64);
  const bfu* Kp   = Kl  + ((size_t)b * 128 * 1024 + h * 64);
  const bfu* LVp  = LVt + (size_t)bh * 64 * 128;
  const f32x4 zero = {0.f, 0.f, 0.f, 0.f};

  float mk[8];
#pragma unroll
  for (int kt = 0; kt < 8; ++kt) mk[kt] = mask[kt * 16 + c];

  f32x4 sacc[8];
#pragma unroll
  for (int kt = 0; kt < 8; ++kt) sacc[kt] = zero;
  __builtin_amdgcn_s_setprio(1);
#pragma unroll
  for (int kk = 0; kk < 2; ++kk) {
    short8 aq = *reinterpret_cast<const short8*>(Qp + (size_t)(qt * 16 + c) * 1024 + kk * 32 + g * 8);
#pragma unroll
    for (int kt = 0; kt < 8; ++kt) {
      short8 bk = *reinterpret_cast<const short8*>(Kp + (size_t)(kt * 16 + c) * 1024 + kk * 32 + g * 8);
      sacc[kt] = MFMA16(aq, bk, sacc[kt]);
    }
  }
  __builtin_amdgcn_s_setprio(0);

  char* myPv = (char*)&PvT[0];
  float rs[4] = {0, 0, 0, 0};
  float colacc[8];
#pragma unroll
  for (int kt = 0; kt < 8; ++kt) {
    u16x4 pk;
    float ca = 0.f;
#pragma unroll
    for (int r = 0; r < 4; ++r) {
      float Ev = __expf(fmaf(sacc[kt][r], SCALE_QK, mk[kt]));
      rs[r] += Ev;
      ca += Ev;
      pk[r] = f2bf(Ev);
      *reinterpret_cast<unsigned short*>(myPv + pvt_off(g * 4 + r, 2 * (kt * 16 + c))) = pk[r];
    }
    colacc[kt] = ca;
    *reinterpret_cast<u16x4*>(PT + ((size_t)bh * 128 + kt * 16 + c) * 576 + qt * 16 + g * 4) = pk;
  }
#pragma unroll
  for (int r = 0; r < 4; ++r) {
    rs[r] += __shfl_xor(rs[r], 1);
    rs[r] += __shfl_xor(rs[r], 2);
    rs[r] += __shfl_xor(rs[r], 4);
    rs[r] += __shfl_xor(rs[r], 8);
  }

  short8 av[4];
#pragma unroll
  for (int kc = 0; kc < 4; ++kc)
    av[kc] = *reinterpret_cast<const short8*>(myPv + pvt_off(c, kc * 64 + g * 16));
  f32x4 oxv[4];
#pragma unroll
  for (int dt = 0; dt < 4; ++dt) oxv[dt] = zero;
  __builtin_amdgcn_s_setprio(1);
#pragma unroll
  for (int dt = 0; dt < 4; ++dt)
#pragma unroll
    for (int kc = 0; kc < 4; ++kc) {
      short8 bv = *reinterpret_cast<const short8*>(LVp + (size_t)(dt * 16 + c) * 128 + kc * 32 + g * 8);
      oxv[dt] = MFMA16(av[kc], bv, oxv[dt]);
    }
  __builtin_amdgcn_s_setprio(0);
#pragma unroll
  for (int r = 0; r < 4; ++r) rs[r] = 1.0f / rs[r];

  short* bw = (short*)PvT;
#pragma unroll
  for (int dt = 0; dt < 4; ++dt)
#pragma unroll
    for (int r = 0; r < 4; ++r)
      bw[(g * 4 + r) * 72 + dt * 16 + c] = (short)f2bf(oxv[dt][r] * rs[r]);
#pragma unroll
  for (int half = 0; half < 2; ++half) {
    const int rr = (l >> 3) + half * 8;
    const int cc = (l & 7) * 8;
    short8 vx = *reinterpret_cast<const short8*>(&bw[rr * 72 + cc]);
    *reinterpret_cast<short8*>(xv + (size_t)(b * 576 + qt * 16 + rr) * 1024 + h * 64 + cc) = vx;
  }

#pragma unroll
  for (int kt = 0; kt < 8; ++kt) {
    colacc[kt] += __shfl_xor(colacc[kt], 16);
    colacc[kt] += __shfl_xor(colacc[kt], 32);
  }
  if (g == 0) {
#pragma unroll
    for (int kt = 0; kt < 8; ++kt)
      colpart[(size_t)(bh * 36 + qt) * 128 + kt * 16 + c] = colacc[kt];
  }
}

// ---------------------------------------------------------------- attention stage B: xl = P^T @ VV / colsum
__global__ __launch_bounds__(64) void attn_xl(
    const bfu* __restrict__ PT, const bfu* __restrict__ VVt,
    const float* __restrict__ colpart, bfu* __restrict__ xl)
{
  __shared__ short XL[1168];

  const int blk = blockIdx.x;
  const int bh = blk & 511, kt = blk >> 9;
  const int b = bh >> 4, h = bh & 15;
  const int l = threadIdx.x;
  const int g = l >> 4, c = l & 15;

  const bfu* PTb  = PT  + ((size_t)bh * 128 + kt * 16 + c) * 576;
  const bfu* VVp  = VVt + (size_t)bh * 64 * 576;
  const f32x4 zero = {0.f, 0.f, 0.f, 0.f};

  float s = 0.f;
  const float* cp = colpart + (size_t)bh * 36 * 128 + kt * 16 + c;
#pragma unroll
  for (int qc = 0; qc < 36; ++qc) s += cp[qc * 128];
  float sinv = 1.0f / s;
  float ci[4];
#pragma unroll
  for (int r = 0; r < 4; ++r) ci[r] = __shfl(sinv, g * 4 + r);

  f32x4 acc[4];
#pragma unroll
  for (int dt = 0; dt < 4; ++dt) acc[dt] = zero;

  __builtin_amdgcn_s_setprio(1);
  for (int p = 0; p < 18; ++p) {
    short8 ap = *reinterpret_cast<const short8*>(PTb + p * 32 + g * 8);
#pragma unroll
    for (int dt = 0; dt < 4; ++dt) {
      short8 bv = *reinterpret_cast<const short8*>(VVp + (size_t)(dt * 16 + c) * 576 + p * 32 + g * 8);
      acc[dt] = MFMA16(ap, bv, acc[dt]);
    }
  }
  __builtin_amdgcn_s_setprio(0);

#pragma unroll
  for (int dt = 0; dt < 4; ++dt)
#pragma unroll
    for (int r = 0; r < 4; ++r)
      XL[(g * 4 + r) * 72 + dt * 16 + c] = (short)f2bf(acc[dt][r] * ci[r]);
#pragma unroll
  for (int half = 0; half < 2; ++half) {
    const int rr = (l >> 3) + half * 8;
    const int cc = (l & 7) * 8;
    short8 vx = *reinterpret_cast<const short8*>(&XL[rr * 72 + cc]);
    *reinterpret_cast<short8*>(xl + (size_t)(b * 128 + kt * 16 + rr) * 1024 + h * 64 + cc) = vx;
  }
}

// ---------------------------------------------------------------- host
static inline int cvt_grid(int n4) {
  int g = (n4 + 255) / 256;
  return g > 4096 ? 4096 : g;
}

extern "C" void kernel_launch(void* const* d_in, const int* in_sizes, int n_in,
                              void* d_out, int out_size, void* d_ws, size_t ws_size,
                              hipStream_t stream)
{
  const float* v    = (const float*)d_in[0];
  const float* lx   = (const float*)d_in[1];
  const float* mask = (const float*)d_in[2];
  const float* Wvq  = (const float*)d_in[3];
  const float* bvq  = (const float*)d_in[4];
  const float* Wlk  = (const float*)d_in[5];
  const float* blk  = (const float*)d_in[6];
  const float* Wvv  = (const float*)d_in[7];
  const float* bvv  = (const float*)d_in[8];
  const float* Wlv  = (const float*)d_in[9];
  const float* blv  = (const float*)d_in[10];
  const float* Wvo  = (const float*)d_in[11];
  const float* bvo  = (const float*)d_in[12];
  const float* Wlo  = (const float*)d_in[13];
  const float* blo  = (const float*)d_in[14];

  float* out_xv = (float*)d_out;                       // 18432 x 1024
  float* out_xl = out_xv + (size_t)18432 * 1024;       // 4096 x 768

  bfu* ws   = (bfu*)d_ws;
  bfu* vb   = ws;                      // 18874368 (later aliased as xv bf16)
  bfu* lb   = vb   + 18874368;         // 3145728  (later aliased by colpart)
  bfu* wqv  = lb   + 3145728;          // 2097152  [Wvq ; Wvv] (2048x1024)
  bfu* wklv = wqv  + 2097152;          // 1572864  [Wlk ; Wlv] (2048x768)
  bfu* wvo  = wklv + 1572864;          // 1048576
  bfu* wlo  = wvo  + 1048576;          // 786432
  bfu* Qb   = wlo  + 786432;           // 18874368  [18432][1024] bf16
  bfu* VVt  = Qb   + 18874368;         // 18874368  [bh][64][576]
  bfu* Kb   = VVt  + 18874368;         // 4194304   [4096][1024] (later aliased as xl bf16)
  bfu* LVt  = Kb   + 4194304;          // 4194304   [bh][64][128]
  bfu* PT   = LVt  + 4194304;          // 37748736  [bh][128][576]
  float* biasqv = (float*)(PT + 37748736);   // 2048 f32  [bvq ; bvv]
  float* biaskl = biasqv + 2048;             // 2048 f32  [blk ; blv]
  float* colpart = (float*)lb;               // 512*36*128 f32, aliases lb/wqv (dead by then)

  // 1) converts + bias concat
  cvt_f32_bf16<<<cvt_grid(18874368 / 4), 256, 0, stream>>>(v, vb, 18874368 / 4);
  CvtArgs ca;
  ca.src[0] = lx;  ca.dst[0] = lb;             ca.n4[0] = 3145728 / 4;
  ca.src[1] = Wvq; ca.dst[1] = wqv;            ca.n4[1] = 1048576 / 4;
  ca.src[2] = Wvv; ca.dst[2] = wqv + 1048576;  ca.n4[2] = 1048576 / 4;
  ca.src[3] = Wlk; ca.dst[3] = wklv;           ca.n4[3] = 786432 / 4;
  ca.src[4] = Wlv; ca.dst[4] = wklv + 786432;  ca.n4[4] = 786432 / 4;
  ca.src[5] = Wvo; ca.dst[5] = wvo;            ca.n4[5] = 1048576 / 4;
  ca.src[6] = Wlo; ca.dst[6] = wlo;            ca.n4[6] = 786432 / 4;
  cvt_multi<<<dim3(1024, 7), 256, 0, stream>>>(ca);
  hipMemcpyAsync(biasqv,        bvq, 1024 * sizeof(float), hipMemcpyDeviceToDevice, stream);
  hipMemcpyAsync(biasqv + 1024, bvv, 1024 * sizeof(float), hipMemcpyDeviceToDevice, stream);
  hipMemcpyAsync(biaskl,        blk, 1024 * sizeof(float), hipMemcpyDeviceToDevice, stream);
  hipMemcpyAsync(biaskl + 1024, blv, 1024 * sizeof(float), hipMemcpyDeviceToDevice, stream);

  // 2) projections: QV on the deep-pipelined 256-tile kernel; KL on the 128-tile kernel
  gemm256<576><<<72 * 8, 512, 0, stream>>>(vb, wqv, biasqv, Qb, nullptr, VVt, 1024, 1024,
                                           18432, 2048, 1024, 8);
  gemm_bt<<<32 * 16, 256, 0, stream>>>(lb, wklv, biaskl, Kb, nullptr, LVt, 128, 1024, 1024,
                                       4096, 2048, 768, 16);

  // 3) attention: 1-wave blocks (xv -> vb alias, xl -> Kb alias)
  attn_xv<<<512 * 36, 64, 0, stream>>>(Qb, Kb, LVt, mask, vb, PT, colpart);
  attn_xl<<<512 * 8,  64, 0, stream>>>(PT, VVt, colpart, Kb);

  // 4) output GEMMs: out_xv on 256-tile kernel (f32), out_xl on 128-tile
  gemm256<0><<<72 * 4, 512, 0, stream>>>(vb, wvo, bvo, nullptr, out_xv, nullptr, 1 << 30, 1024,
                                         18432, 1024, 1024, 4);
  gemm_bt<<<32 * 6, 256, 0, stream>>>(Kb, wlo, blo, nullptr, out_xl, nullptr, 0, 768, 768,
                                      4096, 768, 1024, 6);
}

// Round 9
// 345.482 us; speedup vs baseline: 1.2020x; 1.2020x over previous
//
#include <hip/hip_runtime.h>
#include <stdint.h>

// BiMultiHeadAttention (GLIP bi-attention), MI355X bf16 MFMA pipeline.
// B=32 VN=576 LN=128 E=1024 H=16 D=64, V_DIM=1024 L_DIM=768, SCALE=0.25.

typedef unsigned short bfu;   // bf16 storage
typedef __attribute__((ext_vector_type(4))) float f32x4;
typedef __attribute__((ext_vector_type(8))) short short8;
typedef __attribute__((ext_vector_type(4))) unsigned short u16x4;

#define MFMA16(a,b,c) __builtin_amdgcn_mfma_f32_16x16x32_bf16((a),(b),(c),0,0,0)
#define SCALE_QK 0.25f

__device__ __forceinline__ unsigned short f2bf(float x) {
  unsigned int u = __float_as_uint(x);
  u += 0x7fffu + ((u >> 16) & 1u);   // round-to-nearest-even
  return (unsigned short)(u >> 16);
}

__device__ __forceinline__ void gload_lds16(const void* g, void* l) {
  __builtin_amdgcn_global_load_lds(
      reinterpret_cast<__attribute__((address_space(1))) void*>(
          reinterpret_cast<uintptr_t>(g)),
      reinterpret_cast<__attribute__((address_space(3))) void*>(
          (uint32_t)reinterpret_cast<uintptr_t>(l)),
      16, 0, 0);
}

// ---------------------------------------------------------------- converts
__global__ void cvt_f32_bf16(const float* __restrict__ x, bfu* __restrict__ y, int n4) {
  for (int i = blockIdx.x * blockDim.x + threadIdx.x; i < n4; i += gridDim.x * blockDim.x) {
    const float4 f = *reinterpret_cast<const float4*>(x + (size_t)i * 4);
    u16x4 o;
    o[0] = f2bf(f.x); o[1] = f2bf(f.y); o[2] = f2bf(f.z); o[3] = f2bf(f.w);
    *reinterpret_cast<u16x4*>(y + (size_t)i * 4) = o;
  }
}

struct CvtArgs {
  const float* src[7];
  bfu* dst[7];
  int n4[7];
};

__global__ void cvt_multi(CvtArgs a) {
  const int s = blockIdx.y;
  const float* __restrict__ x = a.src[s];
  bfu* __restrict__ y = a.dst[s];
  const int n4 = a.n4[s];
  for (int i = blockIdx.x * blockDim.x + threadIdx.x; i < n4; i += gridDim.x * blockDim.x) {
    const float4 f = *reinterpret_cast<const float4*>(x + (size_t)i * 4);
    u16x4 o;
    o[0] = f2bf(f.x); o[1] = f2bf(f.y); o[2] = f2bf(f.z); o[3] = f2bf(f.w);
    *reinterpret_cast<u16x4*>(y + (size_t)i * 4) = o;
  }
}

// ---------------------------------------------------------------- GEMM 128-tile (m97 structure) — R5 version
__global__ __launch_bounds__(256) void gemm_bt(
    const bfu* __restrict__ A, const bfu* __restrict__ W, const float* __restrict__ bias,
    bfu* __restrict__ Cb, float* __restrict__ Cf, bfu* __restrict__ Ct, int R, int colsplit,
    int ldc, int M, int N, int K, int nbn)
{
  __shared__ bfu As[128 * 32];
  __shared__ bfu Bs[128 * 32];
  const int nbm = M >> 7;
  const int bid = blockIdx.x;
  int bm, bn;
  if ((nbm & 7) == 0) {             // bijective XCD-aware swizzle
    const int xcd = bid & 7, j = bid >> 3;
    const int jm = j / nbn;
    bm = xcd * (nbm >> 3) + jm;
    bn = j - jm * nbn;
  } else { bm = bid / nbn; bn = bid - (bid / nbn) * nbn; }

  const int t = threadIdx.x, l = t & 63, w = t >> 6;
  const int g = l >> 4, c = l & 15;
  const int wr = (w >> 1) * 64, wc = (w & 1) * 64;

  f32x4 zero = {0.f, 0.f, 0.f, 0.f};
  f32x4 acc[4][4];
  for (int m = 0; m < 4; ++m)
    for (int n = 0; n < 4; ++n) acc[m][n] = zero;

  const int rowA = l >> 2;
  const int kb   = (l & 3) * 16;

  for (int k0 = 0; k0 < K; k0 += 32) {
#pragma unroll
    for (int i = 0; i < 2; ++i) {
      int chunk = w * 2 + i;
      int r = chunk * 16 + rowA;
      const char* ga = (const char*)(A + (size_t)(bm * 128 + r) * K + k0) + kb;
      const char* gb = (const char*)(W + (size_t)(bn * 128 + r) * K + k0) + kb;
      gload_lds16(ga, (char*)As + chunk * 1024);
      gload_lds16(gb, (char*)Bs + chunk * 1024);
    }
    __syncthreads();
    short8 a[4], bf[4];
#pragma unroll
    for (int m = 0; m < 4; ++m)
      a[m] = *reinterpret_cast<const short8*>(&As[(wr + m * 16 + c) * 32 + g * 8]);
#pragma unroll
    for (int n = 0; n < 4; ++n)
      bf[n] = *reinterpret_cast<const short8*>(&Bs[(wc + n * 16 + c) * 32 + g * 8]);
#pragma unroll
    for (int m = 0; m < 4; ++m)
#pragma unroll
      for (int n = 0; n < 4; ++n)
        acc[m][n] = MFMA16(a[m], bf[n], acc[m][n]);
    __syncthreads();
  }

#pragma unroll
  for (int n = 0; n < 4; ++n) {
    const int col = bn * 128 + wc + n * 16 + c;
    const float bs = bias[col];
    if (col >= colsplit) {
      const int colp = col - colsplit;
      const int hh = colp >> 6, dd = colp & 63;
#pragma unroll
      for (int m = 0; m < 4; ++m) {
        const int row0 = bm * 128 + wr + m * 16 + g * 4;
        const int bb = row0 / R, q0 = row0 - bb * R;
        u16x4 pk;
#pragma unroll
        for (int r = 0; r < 4; ++r) pk[r] = f2bf(acc[m][n][r] + bs);
        *reinterpret_cast<u16x4*>(Ct + ((size_t)(bb * 16 + hh) * 64 + dd) * R + q0) = pk;
      }
    } else {
#pragma unroll
      for (int m = 0; m < 4; ++m) {
        const int row0 = bm * 128 + wr + m * 16 + g * 4;
#pragma unroll
        for (int r = 0; r < 4; ++r) {
          float val = acc[m][n][r] + bs;
          size_t idx = (size_t)(row0 + r) * ldc + col;
          if (Cf) Cf[idx] = val;
          else    Cb[idx] = f2bf(val);
        }
      }
    }
  }
}

// ---------------------------------------------------------------- GEMM 256-tile, 8-phase schedule (R7 best)
// BM=BN=256, BK=64, 512 thr (8 waves: wr=w>>2 M-half, wc=w&3 N-quarter).
// LDS 128 KiB: 2 bufs x (A 32KB + B 32KB), 16B-slot XOR swizzle keyed on row&7.
// Counted waits vmcnt(4)/vmcnt(2) -- never 0 in the main loop.
// bf16 epilogues bounce through the dead buf0 LDS region (nt even => last tile uses buf1).
template<int RT>
__global__ __launch_bounds__(512, 2) void gemm256(
    const bfu* __restrict__ A, const bfu* __restrict__ W, const float* __restrict__ bias,
    bfu* __restrict__ Cb, float* __restrict__ Cf, bfu* __restrict__ Ct, int colsplit,
    int ldc, int M, int N, int K, int nbn)
{
  __shared__ bfu lds[65536];          // 131072 B

  const int tid = threadIdx.x;
  const int w = tid >> 6, lane = tid & 63;
  const int g = lane >> 4, c = lane & 15;
  const int wr = w >> 2, wc = w & 3;

  const int nbm = M >> 8;
  int bm, bn;
  { const int xcd = blockIdx.x & 7, j = blockIdx.x >> 3;
    const int jm = j / nbn; bm = xcd * (nbm >> 3) + jm; bn = j - jm * nbn; }

  const int nt = K >> 6;

  const int srow8 = lane >> 3;                     // 0..7
  const int sslot = lane & 7;
  const int swzE  = ((sslot * 16) ^ (srow8 << 4)) >> 1;   // pre-swizzled elem offset in 64-elem row
  const bfu* srcA = A + (size_t)(bm * 256 + 8 * w + srow8) * K + swzE;
  const bfu* srcB = W + (size_t)(bn * 256 + 8 * w + srow8) * K + swzE;

#define AB(cur) (lds + (cur) * 32768)
#define BB(cur) (lds + (cur) * 32768 + 16384)
#define STAGE_A(cur, j, k0) gload_lds16(srcA + (size_t)(64 * (j)) * K + (k0), \
    (void*)(AB(cur) + (64 * (j) + 8 * w) * 64))
#define STAGE_B(cur, j, k0) gload_lds16(srcB + (size_t)(64 * (j)) * K + (k0), \
    (void*)(BB(cur) + (64 * (j) + 8 * w) * 64))

  short8 aF[4][2], bF[4][2];
  const int swzR = ((c & 7) << 3);                 // read-side swizzle (elems)

#define LDA(cur, mh) { _Pragma("unroll") for (int mi2 = 0; mi2 < 4; ++mi2) \
    _Pragma("unroll") for (int ks = 0; ks < 2; ++ks) \
      aF[mi2][ks] = *reinterpret_cast<const short8*>( \
        AB(cur) + (wr * 128 + ((mh) * 4 + mi2) * 16 + c) * 64 + ((ks * 32 + g * 8) ^ swzR)); }
#define LDB(cur, nh) { _Pragma("unroll") for (int ni2 = 0; ni2 < 2; ++ni2) \
    _Pragma("unroll") for (int ks = 0; ks < 2; ++ks) \
      bF[(nh) * 2 + ni2][ks] = *reinterpret_cast<const short8*>( \
        BB(cur) + (wc * 64 + ((nh) * 2 + ni2) * 16 + c) * 64 + ((ks * 32 + g * 8) ^ swzR)); }

  f32x4 acc[8][4];
  const f32x4 zero = {0.f, 0.f, 0.f, 0.f};
#pragma unroll
  for (int mi = 0; mi < 8; ++mi)
#pragma unroll
    for (int ni = 0; ni < 4; ++ni) acc[mi][ni] = zero;

#define PH_MFMA(mh, nh) { __builtin_amdgcn_s_setprio(1); \
    _Pragma("unroll") for (int mi2 = 0; mi2 < 4; ++mi2) \
    _Pragma("unroll") for (int ni2 = 0; ni2 < 2; ++ni2) \
    _Pragma("unroll") for (int ks = 0; ks < 2; ++ks) \
      acc[(mh) * 4 + mi2][(nh) * 2 + ni2] = \
        MFMA16(aF[mi2][ks], bF[(nh) * 2 + ni2][ks], acc[(mh) * 4 + mi2][(nh) * 2 + ni2]); \
    __builtin_amdgcn_s_setprio(0); }

  // ---- prologue: stage tile 0 fully
  STAGE_B(0, 0, 0); STAGE_B(0, 1, 0); STAGE_B(0, 2, 0); STAGE_B(0, 3, 0);
  STAGE_A(0, 0, 0); STAGE_A(0, 1, 0); STAGE_A(0, 2, 0); STAGE_A(0, 3, 0);
  asm volatile("s_waitcnt vmcnt(0)" ::: "memory");
  __builtin_amdgcn_s_barrier();

  int cur = 0;
  for (int t = 0; t < nt - 1; ++t) {
    const int k1 = (t + 1) * 64;
    LDB(cur, 0); LDA(cur, 0);
    STAGE_B(cur ^ 1, 0, k1); STAGE_B(cur ^ 1, 1, k1);
    __builtin_amdgcn_s_barrier();
    PH_MFMA(0, 0);
    __builtin_amdgcn_s_barrier();
    LDB(cur, 1);
    STAGE_B(cur ^ 1, 2, k1); STAGE_B(cur ^ 1, 3, k1);
    asm volatile("s_waitcnt vmcnt(4)" ::: "memory");
    __builtin_amdgcn_s_barrier();
    PH_MFMA(0, 1);
    __builtin_amdgcn_s_barrier();
    LDA(cur, 1);
    STAGE_A(cur ^ 1, 0, k1); STAGE_A(cur ^ 1, 2, k1);
    __builtin_amdgcn_s_barrier();
    PH_MFMA(1, 0);
    __builtin_amdgcn_s_barrier();
    STAGE_A(cur ^ 1, 1, k1); STAGE_A(cur ^ 1, 3, k1);
    asm volatile("s_waitcnt vmcnt(2)" ::: "memory");
    __builtin_amdgcn_s_barrier();
    PH_MFMA(1, 1);
    __builtin_amdgcn_s_barrier();
    cur ^= 1;
  }
  // ---- last tile (no staging); for nt even, cur==1 here (epilogue bounce uses buf0)
  LDB(cur, 0); LDA(cur, 0);
  __builtin_amdgcn_s_barrier();
  PH_MFMA(0, 0);
  __builtin_amdgcn_s_barrier();
  LDB(cur, 1);
  asm volatile("s_waitcnt vmcnt(0)" ::: "memory");
  __builtin_amdgcn_s_barrier();
  PH_MFMA(0, 1);
  __builtin_amdgcn_s_barrier();
  LDA(cur, 1);
  PH_MFMA(1, 0);
  PH_MFMA(1, 1);

  // ---- epilogue (bf16 paths bounce via per-wave region in buf0, 2176 elems/wave)
  short* bw = (short*)lds + w * 2176;
  const bool isCt = (RT > 0) && (bn * 256 >= colsplit);   // block-uniform (colsplit%256==0)

  if (isCt) {
    const int RTl = (RT > 0 ? RT : 1);
#pragma unroll
    for (int ni = 0; ni < 4; ++ni) {
      const float bs = bias[bn * 256 + wc * 64 + ni * 16 + c];
      // tile: rows dd=c (16), cols q-local (128)
#pragma unroll
      for (int mi = 0; mi < 8; ++mi) {
        u16x4 pk;
#pragma unroll
        for (int r = 0; r < 4; ++r) pk[r] = f2bf(acc[mi][ni][r] + bs);
        *reinterpret_cast<u16x4*>(&bw[c * 136 + mi * 16 + g * 4]) = pk;
      }
#pragma unroll
      for (int half = 0; half < 2; ++half)
#pragma unroll
        for (int qh = 0; qh < 2; ++qh) {
          const int dd = (lane >> 3) + half * 8;
          const int ql = (lane & 7) * 8 + qh * 64;
          short8 vx = *reinterpret_cast<const short8*>(&bw[dd * 136 + ql]);
          const int colp = bn * 256 + wc * 64 + ni * 16 + dd - colsplit;
          const int hh = colp >> 6, dl = colp & 63;
          const int qg = bm * 256 + wr * 128 + ql;
          const int bb = qg / RTl, q0 = qg - bb * RTl;
          *reinterpret_cast<short8*>(Ct + ((size_t)(bb * 16 + hh) * 64 + dl) * RTl + q0) = vx;
        }
    }
  } else if (Cf) {
#pragma unroll
    for (int ni = 0; ni < 4; ++ni) {
      const int col = bn * 256 + wc * 64 + ni * 16 + c;
      const float bs = bias[col];
#pragma unroll
      for (int mi = 0; mi < 8; ++mi) {
        const int row0 = bm * 256 + wr * 128 + mi * 16 + g * 4;
#pragma unroll
        for (int r = 0; r < 4; ++r)
          Cf[(size_t)(row0 + r) * ldc + col] = acc[mi][ni][r] + bs;
      }
    }
  } else {
    float bs4[4];
#pragma unroll
    for (int ni = 0; ni < 4; ++ni) bs4[ni] = bias[bn * 256 + wc * 64 + ni * 16 + c];
#pragma unroll
    for (int mi = 0; mi < 8; ++mi) {
#pragma unroll
      for (int ni = 0; ni < 4; ++ni)
#pragma unroll
        for (int r = 0; r < 4; ++r)
          bw[(g * 4 + r) * 72 + ni * 16 + c] = (short)f2bf(acc[mi][ni][r] + bs4[ni]);
#pragma unroll
      for (int half = 0; half < 2; ++half) {
        const int rr = (lane >> 3) + half * 8;
        const int cc2 = (lane & 7) * 8;
        short8 vx = *reinterpret_cast<const short8*>(&bw[rr * 72 + cc2]);
        const int grow = bm * 256 + wr * 128 + mi * 16 + rr;
        *reinterpret_cast<short8*>(Cb + (size_t)grow * ldc + bn * 256 + wc * 64 + cc2) = vx;
      }
    }
  }
#undef AB
#undef BB
#undef STAGE_A
#undef STAGE_B
#undef LDA
#undef LDB
#undef PH_MFMA
}

// ---------------------------------------------------------------- swizzled per-wave P-tile offsets
__device__ __forceinline__ int pvt_off(int q, int kbyte) { return q * 256 + (kbyte ^ ((q & 7) << 4)); }

// ---------------------------------------------------------------- attention stage A: xv + P^T + colsum partials
// 4-wave blocks: grid qc*512 + bh (4608 blocks, 256 threads). K and LV staged once per
// block into LDS (both-sides XOR swizzle, 128B-row pattern verified conflict-free in gemm256).
__global__ __launch_bounds__(256) void attn_xv(
    const bfu* __restrict__ Q, const bfu* __restrict__ Kl,
    const bfu* __restrict__ LVt, const float* __restrict__ mask,
    bfu* __restrict__ xv, bfu* __restrict__ PT, float* __restrict__ colpart)
{
  __shared__ short Ks[128 * 64];      // 16 KB, swizzled: slot s holds global slot s^(k&7)
  __shared__ short LVs[64 * 128];     // 16 KB, swizzled within 128B half-rows
  __shared__ short PvT[4][2048];      // per-wave 16x128 P tile; reused as bounce buf

  const int blk = blockIdx.x;
  const int bh = blk & 511, qc = blk >> 9;   // qc 0..8
  const int b = bh >> 4, h = bh & 15;
  const int t = threadIdx.x, l = t & 63, w = t >> 6;
  const int g = l >> 4, c = l & 15;
  const int qt = qc * 4 + w;                 // qtile 0..35

  const bfu* Qp  = Q   + ((size_t)b * 576 * 1024 + h * 64);
  const bfu* Kp  = Kl  + ((size_t)b * 128 * 1024 + h * 64);
  const bfu* LVp = LVt + (size_t)bh * 64 * 128;
  const f32x4 zero = {0.f, 0.f, 0.f, 0.f};

  // ---- stage K (128x64) and LV (64x128) into LDS, pre-swizzled global source
  {
    const int kr = l >> 3;                       // row-within-chunk 0..7
    const bfu* sK = Kp + (size_t)(w * 8 + kr) * 1024 + (((l & 7) ^ kr) * 8);
#pragma unroll
    for (int i = 0; i < 4; ++i)
      gload_lds16(sK + (size_t)(i * 32) * 1024, (void*)&Ks[(i * 32 + w * 8) * 64]);
    const int lr = l >> 4;                       // row-within-chunk 0..3
    const int key = (w * 4 + lr) & 7;
    const bfu* sLV = LVp + (size_t)(w * 4 + lr) * 128 + ((l >> 3) & 1) * 64 + (((l & 7) ^ key) * 8);
#pragma unroll
    for (int i = 0; i < 4; ++i)
      gload_lds16(sLV + (size_t)(i * 16) * 128, (void*)&LVs[(i * 16 + w * 4) * 128]);
  }
  float mk[8];
#pragma unroll
  for (int kt = 0; kt < 8; ++kt) mk[kt] = mask[kt * 16 + c];
  __syncthreads();

  // ---- S = Q K^T for this 16q x 128k tile (K from LDS)
  f32x4 sacc[8];
#pragma unroll
  for (int kt = 0; kt < 8; ++kt) sacc[kt] = zero;
  __builtin_amdgcn_s_setprio(1);
#pragma unroll
  for (int kk = 0; kk < 2; ++kk) {
    short8 aq = *reinterpret_cast<const short8*>(Qp + (size_t)(qt * 16 + c) * 1024 + kk * 32 + g * 8);
#pragma unroll
    for (int kt = 0; kt < 8; ++kt) {
      short8 bk = *reinterpret_cast<const short8*>(
          &Ks[(kt * 16 + c) * 64 + (((kk * 4 + g) ^ (c & 7)) * 8)]);
      sacc[kt] = MFMA16(aq, bk, sacc[kt]);
    }
  }
  __builtin_amdgcn_s_setprio(0);

  // ---- P = exp(S*scale + mask[k]); write swizzled P tile + PT; accumulate sums
  char* myPv = (char*)&PvT[w][0];
  float rs[4] = {0, 0, 0, 0};
  float colacc[8];
#pragma unroll
  for (int kt = 0; kt < 8; ++kt) {
    u16x4 pk;
    float ca = 0.f;
#pragma unroll
    for (int r = 0; r < 4; ++r) {
      float Ev = __expf(fmaf(sacc[kt][r], SCALE_QK, mk[kt]));
      rs[r] += Ev;
      ca += Ev;
      pk[r] = f2bf(Ev);
      *reinterpret_cast<unsigned short*>(myPv + pvt_off(g * 4 + r, 2 * (kt * 16 + c))) = pk[r];
    }
    colacc[kt] = ca;
    *reinterpret_cast<u16x4*>(PT + ((size_t)bh * 128 + kt * 16 + c) * 576 + qt * 16 + g * 4) = pk;
  }
#pragma unroll
  for (int r = 0; r < 4; ++r) {
    rs[r] += __shfl_xor(rs[r], 1);
    rs[r] += __shfl_xor(rs[r], 2);
    rs[r] += __shfl_xor(rs[r], 4);
    rs[r] += __shfl_xor(rs[r], 8);
  }

  // ---- xv tile = P(16x128) @ LV(128x64)  (LV from LDS)
  short8 av[4];
#pragma unroll
  for (int kc = 0; kc < 4; ++kc)
    av[kc] = *reinterpret_cast<const short8*>(myPv + pvt_off(c, kc * 64 + g * 16));
  f32x4 oxv[4];
#pragma unroll
  for (int dt = 0; dt < 4; ++dt) oxv[dt] = zero;
  __builtin_amdgcn_s_setprio(1);
#pragma unroll
  for (int dt = 0; dt < 4; ++dt)
#pragma unroll
    for (int kc = 0; kc < 4; ++kc) {
      short8 bv = *reinterpret_cast<const short8*>(
          &LVs[(dt * 16 + c) * 128 + (kc >> 1) * 64 + ((((kc & 1) * 4 + g) ^ (c & 7)) * 8)]);
      oxv[dt] = MFMA16(av[kc], bv, oxv[dt]);
    }
  __builtin_amdgcn_s_setprio(0);
#pragma unroll
  for (int r = 0; r < 4; ++r) rs[r] = 1.0f / rs[r];

  // ---- xv store via LDS bounce (PvT dead after av read)
  short* bw = (short*)&PvT[w][0];
#pragma unroll
  for (int dt = 0; dt < 4; ++dt)
#pragma unroll
    for (int r = 0; r < 4; ++r)
      bw[(g * 4 + r) * 72 + dt * 16 + c] = (short)f2bf(oxv[dt][r] * rs[r]);
#pragma unroll
  for (int half = 0; half < 2; ++half) {
    const int rr = (l >> 3) + half * 8;
    const int cc = (l & 7) * 8;
    short8 vx = *reinterpret_cast<const short8*>(&bw[rr * 72 + cc]);
    *reinterpret_cast<short8*>(xv + (size_t)(b * 576 + qt * 16 + rr) * 1024 + h * 64 + cc) = vx;
  }

  // ---- column-sum partial for this 16-q tile (per-wave, no barrier)
#pragma unroll
  for (int kt = 0; kt < 8; ++kt) {
    colacc[kt] += __shfl_xor(colacc[kt], 16);
    colacc[kt] += __shfl_xor(colacc[kt], 32);
  }
  if (g == 0) {
#pragma unroll
    for (int kt = 0; kt < 8; ++kt)
      colpart[(size_t)(bh * 36 + qt) * 128 + kt * 16 + c] = colacc[kt];
  }
}

// ---------------------------------------------------------------- attention stage B: xl = P^T @ VV / colsum
__global__ __launch_bounds__(64) void attn_xl(
    const bfu* __restrict__ PT, const bfu* __restrict__ VVt,
    const float* __restrict__ colpart, bfu* __restrict__ xl)
{
  __shared__ short XL[1168];

  const int blk = blockIdx.x;
  const int bh = blk & 511, kt = blk >> 9;
  const int b = bh >> 4, h = bh & 15;
  const int l = threadIdx.x;
  const int g = l >> 4, c = l & 15;

  const bfu* PTb  = PT  + ((size_t)bh * 128 + kt * 16 + c) * 576;
  const bfu* VVp  = VVt + (size_t)bh * 64 * 576;
  const f32x4 zero = {0.f, 0.f, 0.f, 0.f};

  float s = 0.f;
  const float* cp = colpart + (size_t)bh * 36 * 128 + kt * 16 + c;
#pragma unroll
  for (int qc = 0; qc < 36; ++qc) s += cp[qc * 128];
  float sinv = 1.0f / s;
  float ci[4];
#pragma unroll
  for (int r = 0; r < 4; ++r) ci[r] = __shfl(sinv, g * 4 + r);

  f32x4 acc[4];
#pragma unroll
  for (int dt = 0; dt < 4; ++dt) acc[dt] = zero;

  __builtin_amdgcn_s_setprio(1);
  for (int p = 0; p < 18; ++p) {
    short8 ap = *reinterpret_cast<const short8*>(PTb + p * 32 + g * 8);
#pragma unroll
    for (int dt = 0; dt < 4; ++dt) {
      short8 bv = *reinterpret_cast<const short8*>(VVp + (size_t)(dt * 16 + c) * 576 + p * 32 + g * 8);
      acc[dt] = MFMA16(ap, bv, acc[dt]);
    }
  }
  __builtin_amdgcn_s_setprio(0);

#pragma unroll
  for (int dt = 0; dt < 4; ++dt)
#pragma unroll
    for (int r = 0; r < 4; ++r)
      XL[(g * 4 + r) * 72 + dt * 16 + c] = (short)f2bf(acc[dt][r] * ci[r]);
#pragma unroll
  for (int half = 0; half < 2; ++half) {
    const int rr = (l >> 3) + half * 8;
    const int cc = (l & 7) * 8;
    short8 vx = *reinterpret_cast<const short8*>(&XL[rr * 72 + cc]);
    *reinterpret_cast<short8*>(xl + (size_t)(b * 128 + kt * 16 + rr) * 1024 + h * 64 + cc) = vx;
  }
}

// ---------------------------------------------------------------- host
static inline int cvt_grid(int n4) {
  int g = (n4 + 255) / 256;
  return g > 4096 ? 4096 : g;
}

extern "C" void kernel_launch(void* const* d_in, const int* in_sizes, int n_in,
                              void* d_out, int out_size, void* d_ws, size_t ws_size,
                              hipStream_t stream)
{
  const float* v    = (const float*)d_in[0];
  const float* lx   = (const float*)d_in[1];
  const float* mask = (const float*)d_in[2];
  const float* Wvq  = (const float*)d_in[3];
  const float* bvq  = (const float*)d_in[4];
  const float* Wlk  = (const float*)d_in[5];
  const float* blk  = (const float*)d_in[6];
  const float* Wvv  = (const float*)d_in[7];
  const float* bvv  = (const float*)d_in[8];
  const float* Wlv  = (const float*)d_in[9];
  const float* blv  = (const float*)d_in[10];
  const float* Wvo  = (const float*)d_in[11];
  const float* bvo  = (const float*)d_in[12];
  const float* Wlo  = (const float*)d_in[13];
  const float* blo  = (const float*)d_in[14];

  float* out_xv = (float*)d_out;                       // 18432 x 1024
  float* out_xl = out_xv + (size_t)18432 * 1024;       // 4096 x 768

  bfu* ws   = (bfu*)d_ws;
  bfu* vb   = ws;                      // 18874368 (later aliased as xv bf16)
  bfu* lb   = vb   + 18874368;         // 3145728  (later aliased by colpart)
  bfu* wqv  = lb   + 3145728;          // 2097152  [Wvq ; Wvv] (2048x1024)
  bfu* wklv = wqv  + 2097152;          // 1572864  [Wlk ; Wlv] (2048x768)
  bfu* wvo  = wklv + 1572864;          // 1048576
  bfu* wlo  = wvo  + 1048576;          // 786432
  bfu* Qb   = wlo  + 786432;           // 18874368  [18432][1024] bf16
  bfu* VVt  = Qb   + 18874368;         // 18874368  [bh][64][576]
  bfu* Kb   = VVt  + 18874368;         // 4194304   [4096][1024] (later aliased as xl bf16)
  bfu* LVt  = Kb   + 4194304;          // 4194304   [bh][64][128]
  bfu* PT   = LVt  + 4194304;          // 37748736  [bh][128][576]
  float* biasqv = (float*)(PT + 37748736);   // 2048 f32  [bvq ; bvv]
  float* biaskl = biasqv + 2048;             // 2048 f32  [blk ; blv]
  float* colpart = (float*)lb;               // 512*36*128 f32, aliases lb/wqv (dead by then)

  // 1) converts + bias concat
  cvt_f32_bf16<<<cvt_grid(18874368 / 4), 256, 0, stream>>>(v, vb, 18874368 / 4);
  CvtArgs ca;
  ca.src[0] = lx;  ca.dst[0] = lb;             ca.n4[0] = 3145728 / 4;
  ca.src[1] = Wvq; ca.dst[1] = wqv;            ca.n4[1] = 1048576 / 4;
  ca.src[2] = Wvv; ca.dst[2] = wqv + 1048576;  ca.n4[2] = 1048576 / 4;
  ca.src[3] = Wlk; ca.dst[3] = wklv;           ca.n4[3] = 786432 / 4;
  ca.src[4] = Wlv; ca.dst[4] = wklv + 786432;  ca.n4[4] = 786432 / 4;
  ca.src[5] = Wvo; ca.dst[5] = wvo;            ca.n4[5] = 1048576 / 4;
  ca.src[6] = Wlo; ca.dst[6] = wlo;            ca.n4[6] = 786432 / 4;
  cvt_multi<<<dim3(1024, 7), 256, 0, stream>>>(ca);
  hipMemcpyAsync(biasqv,        bvq, 1024 * sizeof(float), hipMemcpyDeviceToDevice, stream);
  hipMemcpyAsync(biasqv + 1024, bvv, 1024 * sizeof(float), hipMemcpyDeviceToDevice, stream);
  hipMemcpyAsync(biaskl,        blk, 1024 * sizeof(float), hipMemcpyDeviceToDevice, stream);
  hipMemcpyAsync(biaskl + 1024, blv, 1024 * sizeof(float), hipMemcpyDeviceToDevice, stream);

  // 2) projections: QV on 8-phase 256-tile kernel; KL on the 128-tile kernel
  gemm256<576><<<72 * 8, 512, 0, stream>>>(vb, wqv, biasqv, Qb, nullptr, VVt, 1024, 1024,
                                           18432, 2048, 1024, 8);
  gemm_bt<<<32 * 16, 256, 0, stream>>>(lb, wklv, biaskl, Kb, nullptr, LVt, 128, 1024, 1024,
                                       4096, 2048, 768, 16);

  // 3) attention: 4-wave blocks with K/LV in LDS (xv -> vb alias, xl -> Kb alias)
  attn_xv<<<512 * 9, 256, 0, stream>>>(Qb, Kb, LVt, mask, vb, PT, colpart);
  attn_xl<<<512 * 8, 64, 0, stream>>>(PT, VVt, colpart, Kb);

  // 4) output GEMMs: out_xv on 256-tile kernel (f32), out_xl on 128-tile
  gemm256<0><<<72 * 4, 512, 0, stream>>>(vb, wvo, bvo, nullptr, out_xv, nullptr, 1 << 30, 1024,
                                         18432, 1024, 1024, 4);
  gemm_bt<<<32 * 6, 256, 0, stream>>>(Kb, wlo, blo, nullptr, out_xl, nullptr, 0, 768, 768,
                                      4096, 768, 1024, 6);
}